// Round 1
// 294.810 us; speedup vs baseline: 1.0070x; 1.0070x over previous
//
#include <hip/hip_runtime.h>
#include <stdint.h>

#define NN 50000
#define NE 800000
#define GG 782     // gemm grid: (NN + 63) / 64
#define NB 196     // scan blocks: (NN + 255) / 256
#define EB 3125    // edge blocks: NE / 256
#define RR 16      // histogram replicas (atomic-conflict spreading)
#define RZB 3125   // zero blocks: RR*NN / 256

typedef __attribute__((ext_vector_type(8))) short bfx8;   // 8 bf16 (4 VGPRs)
typedef __attribute__((ext_vector_type(4))) float f32x4;  // MFMA acc

// ---- bf16 helpers (RNE) ----
__device__ inline unsigned short f2bf(float f) {
    union { float f; uint32_t u; } x; x.f = f;
    uint32_t u = x.u;
    return (unsigned short)((u + 0x7fffu + ((u >> 16) & 1u)) >> 16);
}
__device__ inline uint32_t pack2bf(float lo, float hi) {
    return (uint32_t)f2bf(lo) | ((uint32_t)f2bf(hi) << 16);
}
__device__ inline float bf2f(unsigned short h) {
    union { uint32_t u; float f; } c; c.u = ((uint32_t)h) << 16;
    return c.f;
}
__device__ inline float2 bfp2f2(uint32_t v) {
    union { uint32_t u; float f; } a, b;
    a.u = (v & 0xffffu) << 16;
    b.u = v & 0xffff0000u;
    return make_float2(a.f, b.f);
}
__device__ inline bfx8 ld8(const unsigned short* p) {
    union { uint4 u; bfx8 v; } c;
    c.u = *(const uint4*)p;
    return c.v;
}
__device__ inline bfx8 cvt8(float4 u, float4 v) {
    union { unsigned short s[8]; bfx8 r; } c;
    c.s[0] = f2bf(u.x); c.s[1] = f2bf(u.y); c.s[2] = f2bf(u.z); c.s[3] = f2bf(u.w);
    c.s[4] = f2bf(v.x); c.s[5] = f2bf(v.y); c.s[6] = f2bf(v.z); c.s[7] = f2bf(v.w);
    return c.r;
}

// ---------- D1: W transposes | zero replicated hist ----------
__global__ void prep(const float* __restrict__ W1, const float* __restrict__ W2,
                     const float* __restrict__ W3,
                     unsigned short* __restrict__ WT1, unsigned short* __restrict__ WT2,
                     unsigned short* __restrict__ WT3, int* __restrict__ hist) {
    int bid = blockIdx.x;
    if (bid < 152) {
        int w = bid * 256 + threadIdx.x;
        if (w < 16384) {
            int nn = w >> 7, k = w & 127;
            WT1[nn * 128 + k] = f2bf(W1[k * 128 + nn]);
        } else if (w < 32768) {
            int w2 = w - 16384, nn = w2 >> 7, k = w2 & 127;
            WT2[nn * 128 + k] = f2bf(W2[k * 128 + nn]);
        } else if (w < 38912) {
            int w2 = w - 32768, nn = w2 >> 7, k = w2 & 127;  // 48x128, zero-pad
            WT3[nn * 128 + k] = (nn < 40) ? f2bf(W3[k * 40 + nn]) : (unsigned short)0;
        }
    } else {
        int i = (bid - 152) * 256 + threadIdx.x;
        if (i < RR * NN) hist[i] = 0;
    }
}

// ---------- D2: layer-1 GEMM (fp32 X, UNSCALED H1) ∪ hist_rank ----------
// gemm1 (~14 us) hides fully under the returning-atomic pass — m114-style
// MFMA/atomic co-scheduling (verified R11: fused dur == bare hist_rank dur).
// R16 replication: atomics spread over 16 hist copies selected by edge-block
// index; drops same-64B-line conflicts 256 -> 16, same-address 16 -> 1.
// Theory: memory-side (MALL) atomic units serialize per line; 17 atomics/ns
// measured is far below fabric transaction ceiling, so conflicts are the limit.
__global__ __launch_bounds__(256) void gemm1_hist(const float* __restrict__ X,
                                                  const unsigned short* __restrict__ WT,
                                                  unsigned short* __restrict__ G, int n,
                                                  const int* __restrict__ dst,
                                                  int* __restrict__ hist,
                                                  unsigned short* __restrict__ rank, int e) {
    if (blockIdx.x >= GG) {
        int be = blockIdx.x - GG;
        int i = be * 256 + threadIdx.x;
        if (i < e) {
            int r = be & (RR - 1);
            rank[i] = (unsigned short)atomicAdd(hist + r * NN + dst[i], 1);
        }
        return;
    }
    int wave = threadIdx.x >> 6;
    int lane = threadIdx.x & 63;
    int quad = lane >> 4;
    int c = lane & 15;
    int rowbase = blockIdx.x * 64 + wave * 16;

    int arow = rowbase + c;
    if (arow >= n) arow = n - 1;
    const float* ap = X + (size_t)arow * 128 + quad * 8;
    bfx8 a[4];
#pragma unroll
    for (int kc = 0; kc < 4; kc++) {
        float4 u = *(const float4*)(ap + kc * 32);
        float4 v = *(const float4*)(ap + kc * 32 + 4);
        a[kc] = cvt8(u, v);
    }

    f32x4 acc[8];
#pragma unroll
    for (int ct = 0; ct < 8; ct++) acc[ct] = (f32x4){0.f, 0.f, 0.f, 0.f};
#pragma unroll
    for (int ct = 0; ct < 8; ct++) {
        const unsigned short* bp = WT + (size_t)(ct * 16 + c) * 128 + quad * 8;
#pragma unroll
        for (int kc = 0; kc < 4; kc++) {
            bfx8 b = ld8(bp + kc * 32);
            acc[ct] = __builtin_amdgcn_mfma_f32_16x16x32_bf16(a[kc], b, acc[ct], 0, 0, 0);
        }
    }

    int r0 = rowbase + quad * 4;
    bool odd = lane & 1;
#pragma unroll
    for (int ct = 0; ct < 8; ct++) {
        float x0 = acc[ct][0], x1 = acc[ct][1], x2 = acc[ct][2], x3 = acc[ct][3];
        float y0 = __shfl_xor(x0, 1, 64), y1 = __shfl_xor(x1, 1, 64);
        float y2 = __shfl_xor(x2, 1, 64), y3 = __shfl_xor(x3, 1, 64);
        int colp = ct * 16 + (c & ~1);
        if (!odd) {
            if (r0 + 0 < n) *(uint32_t*)(&G[(size_t)(r0 + 0) * 128 + colp]) = pack2bf(x0, y0);
            if (r0 + 1 < n) *(uint32_t*)(&G[(size_t)(r0 + 1) * 128 + colp]) = pack2bf(x1, y1);
        } else {
            if (r0 + 2 < n) *(uint32_t*)(&G[(size_t)(r0 + 2) * 128 + colp]) = pack2bf(y2, x2);
            if (r0 + 3 < n) *(uint32_t*)(&G[(size_t)(r0 + 3) * 128 + colp]) = pack2bf(y3, x3);
        }
    }
}

// ---------- D3: fold replicas (deg + per-replica exclusive offsets) + scan + dinv ----------
__global__ void scan_dinv(const int* __restrict__ hist, int* row_ptr, int* bsum,
                          float* dinv, int* __restrict__ deg,
                          unsigned short* __restrict__ repoff, int n) {
    __shared__ int s[256];
    int tid = threadIdx.x;
    int i = blockIdx.x * 256 + tid;
    int v = 0;
    if (i < n) {
        int off = 0;
#pragma unroll
        for (int r = 0; r < RR; r++) {
            int h = hist[r * NN + i];
            repoff[r * NN + i] = (unsigned short)off;  // exclusive prefix over replicas
            off += h;
        }
        v = off;
        deg[i] = v;
    }
    s[tid] = v;
    __syncthreads();
#pragma unroll
    for (int off = 1; off < 256; off <<= 1) {
        int y = (tid >= off) ? s[tid - off] : 0;
        __syncthreads();
        s[tid] += y;
        __syncthreads();
    }
    if (i < n) {
        row_ptr[i] = s[tid] - v;
        dinv[i] = rsqrtf(1.0f + (float)v);
    }
    if (tid == 255) bsum[blockIdx.x] = s[255];
}

// ---------- D4: bucket with inline LDS scan2; last block publishes boff ----------
__global__ void bucket_k(const int* __restrict__ src, const int* __restrict__ dst,
                         const int* __restrict__ row_ptr, const int* __restrict__ bsum,
                         const unsigned short* __restrict__ rank,
                         const unsigned short* __restrict__ repoff,
                         unsigned short* __restrict__ csr_src, int* __restrict__ boff_g,
                         int e) {
    __shared__ int s[256];
    __shared__ int bex[256];
    int tid = threadIdx.x;
    int v = (tid < NB) ? bsum[tid] : 0;
    s[tid] = v;
    __syncthreads();
#pragma unroll
    for (int off = 1; off < 256; off <<= 1) {
        int y = (tid >= off) ? s[tid - off] : 0;
        __syncthreads();
        s[tid] += y;
        __syncthreads();
    }
    bex[tid] = s[tid] - v;
    __syncthreads();

    if (blockIdx.x == gridDim.x - 1) {
        if (tid < NB) boff_g[tid] = bex[tid];
        return;
    }
    int i = blockIdx.x * 256 + tid;
    if (i < e) {
        int d = dst[i];
        int r = blockIdx.x & (RR - 1);  // same replica mapping as gemm1_hist
        csr_src[row_ptr[d] + bex[d >> 8] + (int)repoff[r * NN + d] + (int)rank[i]] =
            (unsigned short)src[i];
    }
}

// ---------- GEMMs for layers 2/3: pre-scale rows by dinv (epilogue) ----------
__global__ __launch_bounds__(256) void gemm128_mfma(const unsigned short* __restrict__ A,
                                                    const unsigned short* __restrict__ WT,
                                                    const float* __restrict__ dinv,
                                                    unsigned short* __restrict__ G, int n) {
    int wave = threadIdx.x >> 6;
    int lane = threadIdx.x & 63;
    int quad = lane >> 4;
    int c = lane & 15;
    int rowbase = blockIdx.x * 64 + wave * 16;

    int arow = rowbase + c;
    if (arow >= n) arow = n - 1;
    const unsigned short* ap = A + (size_t)arow * 128 + quad * 8;
    bfx8 a[4];
#pragma unroll
    for (int kc = 0; kc < 4; kc++) a[kc] = ld8(ap + kc * 32);

    f32x4 acc[8];
#pragma unroll
    for (int ct = 0; ct < 8; ct++) acc[ct] = (f32x4){0.f, 0.f, 0.f, 0.f};
#pragma unroll
    for (int ct = 0; ct < 8; ct++) {
        const unsigned short* bp = WT + (size_t)(ct * 16 + c) * 128 + quad * 8;
#pragma unroll
        for (int kc = 0; kc < 4; kc++) {
            bfx8 b = ld8(bp + kc * 32);
            acc[ct] = __builtin_amdgcn_mfma_f32_16x16x32_bf16(a[kc], b, acc[ct], 0, 0, 0);
        }
    }

    int r0 = rowbase + quad * 4;
    float di[4];
#pragma unroll
    for (int r = 0; r < 4; r++) {
        int rr = r0 + r;
        di[r] = dinv[rr < n ? rr : 0];
    }
    bool odd = lane & 1;
#pragma unroll
    for (int ct = 0; ct < 8; ct++) {
        float x0 = acc[ct][0], x1 = acc[ct][1], x2 = acc[ct][2], x3 = acc[ct][3];
        float y0 = __shfl_xor(x0, 1, 64), y1 = __shfl_xor(x1, 1, 64);
        float y2 = __shfl_xor(x2, 1, 64), y3 = __shfl_xor(x3, 1, 64);
        int colp = ct * 16 + (c & ~1);
        if (!odd) {
            if (r0 + 0 < n) *(uint32_t*)(&G[(size_t)(r0 + 0) * 128 + colp]) = pack2bf(di[0] * x0, di[0] * y0);
            if (r0 + 1 < n) *(uint32_t*)(&G[(size_t)(r0 + 1) * 128 + colp]) = pack2bf(di[1] * x1, di[1] * y1);
        } else {
            if (r0 + 2 < n) *(uint32_t*)(&G[(size_t)(r0 + 2) * 128 + colp]) = pack2bf(di[2] * y2, di[2] * x2);
            if (r0 + 3 < n) *(uint32_t*)(&G[(size_t)(r0 + 3) * 128 + colp]) = pack2bf(di[3] * y3, di[3] * x3);
        }
    }
}

__global__ __launch_bounds__(256) void gemm40_mfma(const unsigned short* __restrict__ A,
                                                   const unsigned short* __restrict__ WT,
                                                   const float* __restrict__ dinv,
                                                   unsigned short* __restrict__ G, int n) {
    int wave = threadIdx.x >> 6;
    int lane = threadIdx.x & 63;
    int quad = lane >> 4;
    int c = lane & 15;
    int rowbase = blockIdx.x * 64 + wave * 16;

    int arow = rowbase + c;
    if (arow >= n) arow = n - 1;
    const unsigned short* ap = A + (size_t)arow * 128 + quad * 8;
    bfx8 a[4];
#pragma unroll
    for (int kc = 0; kc < 4; kc++) a[kc] = ld8(ap + kc * 32);

    f32x4 acc[3];
#pragma unroll
    for (int ct = 0; ct < 3; ct++) acc[ct] = (f32x4){0.f, 0.f, 0.f, 0.f};
#pragma unroll
    for (int ct = 0; ct < 3; ct++) {
        const unsigned short* bp = WT + (size_t)(ct * 16 + c) * 128 + quad * 8;
#pragma unroll
        for (int kc = 0; kc < 4; kc++) {
            bfx8 b = ld8(bp + kc * 32);
            acc[ct] = __builtin_amdgcn_mfma_f32_16x16x32_bf16(a[kc], b, acc[ct], 0, 0, 0);
        }
    }

    int r0 = rowbase + quad * 4;
    float di[4];
#pragma unroll
    for (int r = 0; r < 4; r++) {
        int rr = r0 + r;
        di[r] = dinv[rr < n ? rr : 0];
    }
    bool odd = lane & 1;
#pragma unroll
    for (int ct = 0; ct < 3; ct++) {
        float x0 = acc[ct][0], x1 = acc[ct][1], x2 = acc[ct][2], x3 = acc[ct][3];
        float y0 = __shfl_xor(x0, 1, 64), y1 = __shfl_xor(x1, 1, 64);
        float y2 = __shfl_xor(x2, 1, 64), y3 = __shfl_xor(x3, 1, 64);
        int colp = ct * 16 + (c & ~1);
        if (colp >= 40) continue;
        if (!odd) {
            if (r0 + 0 < n) *(uint32_t*)(&G[(size_t)(r0 + 0) * 40 + colp]) = pack2bf(di[0] * x0, di[0] * y0);
            if (r0 + 1 < n) *(uint32_t*)(&G[(size_t)(r0 + 1) * 40 + colp]) = pack2bf(di[1] * x1, di[1] * y1);
        } else {
            if (r0 + 2 < n) *(uint32_t*)(&G[(size_t)(r0 + 2) * 40 + colp]) = pack2bf(di[2] * y2, di[2] * x2);
            if (r0 + 3 < n) *(uint32_t*)(&G[(size_t)(r0 + 3) * 40 + colp]) = pack2bf(di[3] * y3, di[3] * x3);
        }
    }
}

// ---------- D5: layer-1 aggregate, UNSCALED H1 with per-edge dinv[s] ----------
// 1 wave per node (max TLP — the gather is bandwidth-bound on random rows;
// R12 showed coupling this to GEMM tiles loses 2.5x wave parallelism).
__global__ __launch_bounds__(256) void agg128_l1(const unsigned short* __restrict__ G,
                                                 const int* __restrict__ row_ptr,
                                                 const int* __restrict__ boff,
                                                 const int* __restrict__ hist,
                                                 const unsigned short* __restrict__ csr_src,
                                                 const float* __restrict__ dinv,
                                                 const float* __restrict__ b,
                                                 unsigned short* __restrict__ Y, int n) {
    int node = blockIdx.x * 4 + (threadIdx.x >> 6);
    if (node >= n) return;
    int l = threadIdx.x & 63;
    const uint32_t* Gr = (const uint32_t*)G;

    float dn = dinv[node];
    float2 sf = bfp2f2(Gr[(size_t)node * 64 + l]);
    float2 acc = make_float2(dn * sf.x, dn * sf.y);  // self: dinv[d]*H1[d]
    int p = row_ptr[node] + boff[node >> 8];
    int p1 = p + hist[node];
    for (; p + 7 < p1; p += 8) {
        int s0 = csr_src[p],     s1 = csr_src[p + 1], s2 = csr_src[p + 2], s3 = csr_src[p + 3];
        int s4 = csr_src[p + 4], s5 = csr_src[p + 5], s6 = csr_src[p + 6], s7 = csr_src[p + 7];
        float d0 = dinv[s0], d1 = dinv[s1], d2 = dinv[s2], d3 = dinv[s3];
        float d4 = dinv[s4], d5 = dinv[s5], d6 = dinv[s6], d7 = dinv[s7];
        float2 f0 = bfp2f2(Gr[(size_t)s0 * 64 + l]), f1 = bfp2f2(Gr[(size_t)s1 * 64 + l]);
        float2 f2 = bfp2f2(Gr[(size_t)s2 * 64 + l]), f3 = bfp2f2(Gr[(size_t)s3 * 64 + l]);
        float2 f4 = bfp2f2(Gr[(size_t)s4 * 64 + l]), f5 = bfp2f2(Gr[(size_t)s5 * 64 + l]);
        float2 f6 = bfp2f2(Gr[(size_t)s6 * 64 + l]), f7 = bfp2f2(Gr[(size_t)s7 * 64 + l]);
        acc.x += (fmaf(d0, f0.x, d1 * f1.x) + fmaf(d2, f2.x, d3 * f3.x)) +
                 (fmaf(d4, f4.x, d5 * f5.x) + fmaf(d6, f6.x, d7 * f7.x));
        acc.y += (fmaf(d0, f0.y, d1 * f1.y) + fmaf(d2, f2.y, d3 * f3.y)) +
                 (fmaf(d4, f4.y, d5 * f5.y) + fmaf(d6, f6.y, d7 * f7.y));
    }
    for (; p < p1; ++p) {
        int s = csr_src[p];
        float ds = dinv[s];
        float2 f = bfp2f2(Gr[(size_t)s * 64 + l]);
        acc.x = fmaf(ds, f.x, acc.x);
        acc.y = fmaf(ds, f.y, acc.y);
    }
    float vx = fmaf(dn, acc.x, b[2 * l]);
    float vy = fmaf(dn, acc.y, b[2 * l + 1]);
    ((uint32_t*)Y)[(size_t)node * 64 + l] = pack2bf(vx > 0.f ? vx : 0.f, vy > 0.f ? vy : 0.f);
}

// ---------- D7: layer-2 aggregate (G pre-scaled) ----------
__global__ __launch_bounds__(256) void agg128(const unsigned short* __restrict__ G,
                                              const int* __restrict__ row_ptr,
                                              const int* __restrict__ boff,
                                              const int* __restrict__ hist,
                                              const unsigned short* __restrict__ csr_src,
                                              const float* __restrict__ dinv,
                                              const float* __restrict__ b,
                                              unsigned short* __restrict__ Y, int n) {
    int node = blockIdx.x * 4 + (threadIdx.x >> 6);
    if (node >= n) return;
    int l = threadIdx.x & 63;
    const uint32_t* Gr = (const uint32_t*)G;

    float2 acc = bfp2f2(Gr[(size_t)node * 64 + l]);  // self (pre-scaled)
    int p = row_ptr[node] + boff[node >> 8];
    int p1 = p + hist[node];
    for (; p + 7 < p1; p += 8) {
        int s0 = csr_src[p],     s1 = csr_src[p + 1], s2 = csr_src[p + 2], s3 = csr_src[p + 3];
        int s4 = csr_src[p + 4], s5 = csr_src[p + 5], s6 = csr_src[p + 6], s7 = csr_src[p + 7];
        float2 f0 = bfp2f2(Gr[(size_t)s0 * 64 + l]), f1 = bfp2f2(Gr[(size_t)s1 * 64 + l]);
        float2 f2 = bfp2f2(Gr[(size_t)s2 * 64 + l]), f3 = bfp2f2(Gr[(size_t)s3 * 64 + l]);
        float2 f4 = bfp2f2(Gr[(size_t)s4 * 64 + l]), f5 = bfp2f2(Gr[(size_t)s5 * 64 + l]);
        float2 f6 = bfp2f2(Gr[(size_t)s6 * 64 + l]), f7 = bfp2f2(Gr[(size_t)s7 * 64 + l]);
        acc.x += ((f0.x + f1.x) + (f2.x + f3.x)) + ((f4.x + f5.x) + (f6.x + f7.x));
        acc.y += ((f0.y + f1.y) + (f2.y + f3.y)) + ((f4.y + f5.y) + (f6.y + f7.y));
    }
    for (; p < p1; ++p) {
        float2 f = bfp2f2(Gr[(size_t)csr_src[p] * 64 + l]);
        acc.x += f.x; acc.y += f.y;
    }
    float dn = dinv[node];
    float vx = fmaf(dn, acc.x, b[2 * l]);
    float vy = fmaf(dn, acc.y, b[2 * l + 1]);
    ((uint32_t*)Y)[(size_t)node * 64 + l] = pack2bf(vx > 0.f ? vx : 0.f, vy > 0.f ? vy : 0.f);
}

// ---------- D9: 40-wide aggregate + log_softmax ----------
__global__ __launch_bounds__(256) void agg40_lsm(const unsigned short* __restrict__ G,
                                                 const int* __restrict__ row_ptr,
                                                 const int* __restrict__ boff,
                                                 const int* __restrict__ hist,
                                                 const unsigned short* __restrict__ csr_src,
                                                 const float* __restrict__ dinv,
                                                 const float* __restrict__ b,
                                                 float* __restrict__ Y, int n) {
    int node = blockIdx.x * 4 + (threadIdx.x >> 6);
    if (node >= n) return;
    int lane = threadIdx.x & 63;
    bool act = lane < 40;
    int lc = act ? lane : 0;

    float acc = act ? bf2f(G[(size_t)node * 40 + lane]) : 0.f;
    int p = row_ptr[node] + boff[node >> 8];
    int p1 = p + hist[node];
    for (; p + 3 < p1; p += 4) {
        int s0 = csr_src[p], s1 = csr_src[p + 1], s2 = csr_src[p + 2], s3 = csr_src[p + 3];
        float f0 = bf2f(G[(size_t)s0 * 40 + lc]);
        float f1 = bf2f(G[(size_t)s1 * 40 + lc]);
        float f2 = bf2f(G[(size_t)s2 * 40 + lc]);
        float f3 = bf2f(G[(size_t)s3 * 40 + lc]);
        acc += (f0 + f1) + (f2 + f3);
    }
    for (; p < p1; ++p) acc += bf2f(G[(size_t)csr_src[p] * 40 + lc]);

    float v = act ? fmaf(dinv[node], acc, b[lane]) : -1e30f;
    float m = v;
#pragma unroll
    for (int off = 32; off > 0; off >>= 1) m = fmaxf(m, __shfl_xor(m, off, 64));
    float ex = act ? expf(v - m) : 0.f;
    float s_ = ex;
#pragma unroll
    for (int off = 32; off > 0; off >>= 1) s_ += __shfl_xor(s_, off, 64);
    float ls = logf(s_);
    if (act) Y[(size_t)node * 40 + lane] = v - m - ls;
}

// ---------- launch ----------

extern "C" void kernel_launch(void* const* d_in, const int* in_sizes, int n_in,
                              void* d_out, int out_size, void* d_ws, size_t ws_size,
                              hipStream_t stream) {
    const float* x  = (const float*)d_in[0];
    const int*   ei = (const int*)d_in[1];
    const float* W1 = (const float*)d_in[2];
    const float* b1 = (const float*)d_in[3];
    const float* W2 = (const float*)d_in[4];
    const float* b2 = (const float*)d_in[5];
    const float* W3 = (const float*)d_in[6];
    const float* b3 = (const float*)d_in[7];
    float* out = (float*)d_out;

    const int n = NN, e = NE;
    const int* srcI = ei;
    const int* dstI = ei + e;

    char* ws = (char*)d_ws;
    int*            deg     = (int*)ws;                          // n ints (written by scan)
    int*            row_ptr = (int*)(ws + 200704);               // n ints
    int*            bsum    = (int*)(ws + 401408);               // 256
    int*            boff    = (int*)(ws + 402432);               // 256
    float*          dinv    = (float*)(ws + 403456);             // n fp32
    unsigned short* rank    = (unsigned short*)(ws + 604160);    // E ushort
    unsigned short* csr_src = (unsigned short*)(ws + 2204160);   // E ushort
    unsigned short* WT1     = (unsigned short*)(ws + 3804160);   // 128x128 bf16
    unsigned short* WT2     = (unsigned short*)(ws + 3836928);
    unsigned short* WT3     = (unsigned short*)(ws + 3869696);   // 48x128 bf16
    unsigned short* bufG    = (unsigned short*)(ws + 3881984);   // n*128 bf16
    unsigned short* bufA    = (unsigned short*)(ws + 16681984);  // n*128 bf16
    // hist replicas + repoff alias bufA's space: dead after D4, bufA first
    // written in D5 (stream-ordered, fully overwritten).
    int*            hist16  = (int*)(ws + 16681984);             // RR*n ints (3.2MB)
    unsigned short* repoff  = (unsigned short*)(ws + 16681984 + RR * NN * 4);  // RR*n ushort (1.6MB)

    // D1: W transposes + zero replicated hist
    prep<<<152 + RZB, 256, 0, stream>>>(W1, W2, W3, WT1, WT2, WT3, hist16);
    // D2: layer-1 GEMM (unscaled) ∪ histogram+ranks (R16 replicated)
    gemm1_hist<<<GG + EB, 256, 0, stream>>>(x, WT1, bufG, n, dstI, hist16, rank, e);
    // D3: fold replicas + scan pieces + dinv
    scan_dinv<<<NB, 256, 0, stream>>>(hist16, row_ptr, bsum, dinv, deg, repoff, n);
    // D4: bucket (inline scan2) + boff publish
    bucket_k<<<EB + 1, 256, 0, stream>>>(srcI, dstI, row_ptr, bsum, rank, repoff, csr_src, boff, e);
    // D5: aggregate layer 1 (per-edge dinv)
    agg128_l1<<<(n + 3) / 4, 256, 0, stream>>>(bufG, row_ptr, boff, deg, csr_src, dinv, b1, bufA, n);
    // D6: layer-2 GEMM (pre-scaled)
    gemm128_mfma<<<GG, 256, 0, stream>>>(bufA, WT2, dinv, bufG, n);
    // D7: aggregate layer 2
    agg128<<<(n + 3) / 4, 256, 0, stream>>>(bufG, row_ptr, boff, deg, csr_src, dinv, b2, bufA, n);
    // D8: layer-3 GEMM (40-wide, pre-scaled)
    gemm40_mfma<<<GG, 256, 0, stream>>>(bufA, WT3, dinv, bufG, n);
    // D9: aggregate + log_softmax -> out
    agg40_lsm<<<(n + 3) / 4, 256, 0, stream>>>(bufG, row_ptr, boff, deg, csr_src, dinv, b3, out, n);
}

// Round 2
// 290.739 us; speedup vs baseline: 1.0211x; 1.0140x over previous
//
#include <hip/hip_runtime.h>
#include <stdint.h>

#define NN 50000
#define NE 800000
#define GG 782     // gemm grid: (NN + 63) / 64
#define NB 196     // hi buckets: ceil(NN / 256)
#define TT 8192    // edges per hist/scatter block
#define TB 98      // edge blocks: ceil(NE / TT)

typedef __attribute__((ext_vector_type(8))) short bfx8;   // 8 bf16 (4 VGPRs)
typedef __attribute__((ext_vector_type(4))) float f32x4;  // MFMA acc

// ---- bf16 helpers (RNE) ----
__device__ inline unsigned short f2bf(float f) {
    union { float f; uint32_t u; } x; x.f = f;
    uint32_t u = x.u;
    return (unsigned short)((u + 0x7fffu + ((u >> 16) & 1u)) >> 16);
}
__device__ inline uint32_t pack2bf(float lo, float hi) {
    return (uint32_t)f2bf(lo) | ((uint32_t)f2bf(hi) << 16);
}
__device__ inline float bf2f(unsigned short h) {
    union { uint32_t u; float f; } c; c.u = ((uint32_t)h) << 16;
    return c.f;
}
__device__ inline float2 bfp2f2(uint32_t v) {
    union { uint32_t u; float f; } a, b;
    a.u = (v & 0xffffu) << 16;
    b.u = v & 0xffff0000u;
    return make_float2(a.f, b.f);
}
__device__ inline bfx8 ld8(const unsigned short* p) {
    union { uint4 u; bfx8 v; } c;
    c.u = *(const uint4*)p;
    return c.v;
}
__device__ inline bfx8 cvt8(float4 u, float4 v) {
    union { unsigned short s[8]; bfx8 r; } c;
    c.s[0] = f2bf(u.x); c.s[1] = f2bf(u.y); c.s[2] = f2bf(u.z); c.s[3] = f2bf(u.w);
    c.s[4] = f2bf(v.x); c.s[5] = f2bf(v.y); c.s[6] = f2bf(v.z); c.s[7] = f2bf(v.w);
    return c.r;
}

// ---------- D1: W transposes (no histogram zeroing needed anymore) ----------
__global__ void prep(const float* __restrict__ W1, const float* __restrict__ W2,
                     const float* __restrict__ W3,
                     unsigned short* __restrict__ WT1, unsigned short* __restrict__ WT2,
                     unsigned short* __restrict__ WT3) {
    int w = blockIdx.x * 256 + threadIdx.x;
    if (w < 16384) {
        int nn = w >> 7, k = w & 127;
        WT1[nn * 128 + k] = f2bf(W1[k * 128 + nn]);
    } else if (w < 32768) {
        int w2 = w - 16384, nn = w2 >> 7, k = w2 & 127;
        WT2[nn * 128 + k] = f2bf(W2[k * 128 + nn]);
    } else if (w < 38912) {
        int w2 = w - 32768, nn = w2 >> 7, k = w2 & 127;  // 48x128, zero-pad
        WT3[nn * 128 + k] = (nn < 40) ? f2bf(W3[k * 40 + nn]) : (unsigned short)0;
    }
}

// ---------- D2: layer-1 GEMM (fp32 X, UNSCALED H1) ∪ coarse LDS histogram ----------
// R1 post-mortem: 800K returning DEVICE-scope atomics cost ~44us regardless of
// address spreading (per-transaction memory-side cost, WRITE_SIZE showed ~21MB
// of atomic line traffic). Replaced with a zero-global-atomic counting sort:
// here, per-(block, hi=dst>>8) counts via LDS-only histogram.
__global__ __launch_bounds__(256) void gemm1_hist(const float* __restrict__ X,
                                                  const unsigned short* __restrict__ WT,
                                                  unsigned short* __restrict__ G, int n,
                                                  const int* __restrict__ dst,
                                                  int* __restrict__ counts, int e) {
    if (blockIdx.x >= GG) {
        int b = blockIdx.x - GG;
        __shared__ int h[256];
        h[threadIdx.x] = 0;
        __syncthreads();
        int start = b * TT;
        int end = start + TT; if (end > e) end = e;
        for (int i = start + threadIdx.x; i < end; i += 256)
            atomicAdd(&h[dst[i] >> 8], 1);  // LDS atomic — never touches HBM
        __syncthreads();
        int d = threadIdx.x;
        if (d < NB) counts[d * TB + b] = h[d];
        return;
    }
    int wave = threadIdx.x >> 6;
    int lane = threadIdx.x & 63;
    int quad = lane >> 4;
    int c = lane & 15;
    int rowbase = blockIdx.x * 64 + wave * 16;

    int arow = rowbase + c;
    if (arow >= n) arow = n - 1;
    const float* ap = X + (size_t)arow * 128 + quad * 8;
    bfx8 a[4];
#pragma unroll
    for (int kc = 0; kc < 4; kc++) {
        float4 u = *(const float4*)(ap + kc * 32);
        float4 v = *(const float4*)(ap + kc * 32 + 4);
        a[kc] = cvt8(u, v);
    }

    f32x4 acc[8];
#pragma unroll
    for (int ct = 0; ct < 8; ct++) acc[ct] = (f32x4){0.f, 0.f, 0.f, 0.f};
#pragma unroll
    for (int ct = 0; ct < 8; ct++) {
        const unsigned short* bp = WT + (size_t)(ct * 16 + c) * 128 + quad * 8;
#pragma unroll
        for (int kc = 0; kc < 4; kc++) {
            bfx8 b = ld8(bp + kc * 32);
            acc[ct] = __builtin_amdgcn_mfma_f32_16x16x32_bf16(a[kc], b, acc[ct], 0, 0, 0);
        }
    }

    int r0 = rowbase + quad * 4;
    bool odd = lane & 1;
#pragma unroll
    for (int ct = 0; ct < 8; ct++) {
        float x0 = acc[ct][0], x1 = acc[ct][1], x2 = acc[ct][2], x3 = acc[ct][3];
        float y0 = __shfl_xor(x0, 1, 64), y1 = __shfl_xor(x1, 1, 64);
        float y2 = __shfl_xor(x2, 1, 64), y3 = __shfl_xor(x3, 1, 64);
        int colp = ct * 16 + (c & ~1);
        if (!odd) {
            if (r0 + 0 < n) *(uint32_t*)(&G[(size_t)(r0 + 0) * 128 + colp]) = pack2bf(x0, y0);
            if (r0 + 1 < n) *(uint32_t*)(&G[(size_t)(r0 + 1) * 128 + colp]) = pack2bf(x1, y1);
        } else {
            if (r0 + 2 < n) *(uint32_t*)(&G[(size_t)(r0 + 2) * 128 + colp]) = pack2bf(y2, x2);
            if (r0 + 3 < n) *(uint32_t*)(&G[(size_t)(r0 + 3) * 128 + colp]) = pack2bf(y3, x3);
        }
    }
}

// ---------- D3: exclusive scan of counts[NB][TB]; bucket bases base196[0..NB] ----------
__global__ void scanA(int* __restrict__ counts, int* __restrict__ base196) {
    __shared__ int s[256];
    int d = threadIdx.x;
    int run = 0;
    if (d < NB) {
        for (int b0 = 0; b0 < TB; b0 += 14) {  // TB=98 -> 7 iters, loads batched for MLP
            int c[14];
#pragma unroll
            for (int j = 0; j < 14; j++) {
                int b = b0 + j;
                c[j] = (b < TB) ? counts[d * TB + b] : 0;
            }
#pragma unroll
            for (int j = 0; j < 14; j++) {
                int b = b0 + j;
                if (b < TB) counts[d * TB + b] = run;
                run += c[j];
            }
        }
    }
    int v = run;
    s[d] = v;
    __syncthreads();
#pragma unroll
    for (int off = 1; off < 256; off <<= 1) {
        int y = (d >= off) ? s[d - off] : 0;
        __syncthreads();
        s[d] += y;
        __syncthreads();
    }
    if (d <= NB) base196[d] = s[d] - v;  // d<NB: exclusive base; d==NB: total (=e)
}

// ---------- D4: partition edges into hi buckets (LDS ranks only) ----------
__global__ __launch_bounds__(256) void scatterA(const int* __restrict__ src,
                                                const int* __restrict__ dst,
                                                const int* __restrict__ counts,
                                                const int* __restrict__ base196,
                                                uint32_t* __restrict__ packA, int e) {
    __shared__ int gb[256];
    __shared__ int lc[256];
    int t = threadIdx.x;
    if (t < NB) {
        gb[t] = base196[t] + counts[t * TB + blockIdx.x];
        lc[t] = 0;
    }
    __syncthreads();
    int start = blockIdx.x * TT;
    int end = start + TT; if (end > e) end = e;
    for (int i = start + t; i < end; i += 256) {
        int d = dst[i];
        int s = src[i];
        int hi = d >> 8;
        int r = atomicAdd(&lc[hi], 1);  // LDS
        packA[gb[hi] + r] = ((uint32_t)d << 16) | (uint32_t)s;
    }
}

// ---------- D5: per-bucket fine sort -> row_ptr/deg/dinv + csr_src ----------
__global__ __launch_bounds__(256) void buildB(const uint32_t* __restrict__ packA,
                                              const int* __restrict__ base196,
                                              int* __restrict__ row_ptr, int* __restrict__ deg,
                                              float* __restrict__ dinv,
                                              unsigned short* __restrict__ csr_src, int n) {
    __shared__ int cnt[256];
    __shared__ int s[256];
    __shared__ int rp[256];
    int hi = blockIdx.x;
    int t = threadIdx.x;
    cnt[t] = 0;
    __syncthreads();
    int b0 = base196[hi], b1 = base196[hi + 1];
    for (int i = b0 + t; i < b1; i += 256)
        atomicAdd(&cnt[(packA[i] >> 16) & 0xFF], 1);  // LDS
    __syncthreads();
    int v = cnt[t];
    s[t] = v;
    __syncthreads();
#pragma unroll
    for (int off = 1; off < 256; off <<= 1) {
        int y = (t >= off) ? s[t - off] : 0;
        __syncthreads();
        s[t] += y;
        __syncthreads();
    }
    rp[t] = b0 + s[t] - v;  // absolute row start for node hi*256+t
    int node = hi * 256 + t;
    if (node < n) {
        row_ptr[node] = rp[t];
        deg[node] = v;
        dinv[node] = rsqrtf(1.0f + (float)v);
    }
    cnt[t] = 0;
    __syncthreads();
    for (int i = b0 + t; i < b1; i += 256) {
        uint32_t p = packA[i];
        int lo = (p >> 16) & 0xFF;
        int r = atomicAdd(&cnt[lo], 1);  // LDS
        csr_src[rp[lo] + r] = (unsigned short)(p & 0xFFFF);
    }
}

// ---------- GEMMs for layers 2/3: pre-scale rows by dinv (epilogue) ----------
__global__ __launch_bounds__(256) void gemm128_mfma(const unsigned short* __restrict__ A,
                                                    const unsigned short* __restrict__ WT,
                                                    const float* __restrict__ dinv,
                                                    unsigned short* __restrict__ G, int n) {
    int wave = threadIdx.x >> 6;
    int lane = threadIdx.x & 63;
    int quad = lane >> 4;
    int c = lane & 15;
    int rowbase = blockIdx.x * 64 + wave * 16;

    int arow = rowbase + c;
    if (arow >= n) arow = n - 1;
    const unsigned short* ap = A + (size_t)arow * 128 + quad * 8;
    bfx8 a[4];
#pragma unroll
    for (int kc = 0; kc < 4; kc++) a[kc] = ld8(ap + kc * 32);

    f32x4 acc[8];
#pragma unroll
    for (int ct = 0; ct < 8; ct++) acc[ct] = (f32x4){0.f, 0.f, 0.f, 0.f};
#pragma unroll
    for (int ct = 0; ct < 8; ct++) {
        const unsigned short* bp = WT + (size_t)(ct * 16 + c) * 128 + quad * 8;
#pragma unroll
        for (int kc = 0; kc < 4; kc++) {
            bfx8 b = ld8(bp + kc * 32);
            acc[ct] = __builtin_amdgcn_mfma_f32_16x16x32_bf16(a[kc], b, acc[ct], 0, 0, 0);
        }
    }

    int r0 = rowbase + quad * 4;
    float di[4];
#pragma unroll
    for (int r = 0; r < 4; r++) {
        int rr = r0 + r;
        di[r] = dinv[rr < n ? rr : 0];
    }
    bool odd = lane & 1;
#pragma unroll
    for (int ct = 0; ct < 8; ct++) {
        float x0 = acc[ct][0], x1 = acc[ct][1], x2 = acc[ct][2], x3 = acc[ct][3];
        float y0 = __shfl_xor(x0, 1, 64), y1 = __shfl_xor(x1, 1, 64);
        float y2 = __shfl_xor(x2, 1, 64), y3 = __shfl_xor(x3, 1, 64);
        int colp = ct * 16 + (c & ~1);
        if (!odd) {
            if (r0 + 0 < n) *(uint32_t*)(&G[(size_t)(r0 + 0) * 128 + colp]) = pack2bf(di[0] * x0, di[0] * y0);
            if (r0 + 1 < n) *(uint32_t*)(&G[(size_t)(r0 + 1) * 128 + colp]) = pack2bf(di[1] * x1, di[1] * y1);
        } else {
            if (r0 + 2 < n) *(uint32_t*)(&G[(size_t)(r0 + 2) * 128 + colp]) = pack2bf(di[2] * y2, di[2] * x2);
            if (r0 + 3 < n) *(uint32_t*)(&G[(size_t)(r0 + 3) * 128 + colp]) = pack2bf(di[3] * y3, di[3] * x3);
        }
    }
}

__global__ __launch_bounds__(256) void gemm40_mfma(const unsigned short* __restrict__ A,
                                                   const unsigned short* __restrict__ WT,
                                                   const float* __restrict__ dinv,
                                                   unsigned short* __restrict__ G, int n) {
    int wave = threadIdx.x >> 6;
    int lane = threadIdx.x & 63;
    int quad = lane >> 4;
    int c = lane & 15;
    int rowbase = blockIdx.x * 64 + wave * 16;

    int arow = rowbase + c;
    if (arow >= n) arow = n - 1;
    const unsigned short* ap = A + (size_t)arow * 128 + quad * 8;
    bfx8 a[4];
#pragma unroll
    for (int kc = 0; kc < 4; kc++) a[kc] = ld8(ap + kc * 32);

    f32x4 acc[3];
#pragma unroll
    for (int ct = 0; ct < 3; ct++) acc[ct] = (f32x4){0.f, 0.f, 0.f, 0.f};
#pragma unroll
    for (int ct = 0; ct < 3; ct++) {
        const unsigned short* bp = WT + (size_t)(ct * 16 + c) * 128 + quad * 8;
#pragma unroll
        for (int kc = 0; kc < 4; kc++) {
            bfx8 b = ld8(bp + kc * 32);
            acc[ct] = __builtin_amdgcn_mfma_f32_16x16x32_bf16(a[kc], b, acc[ct], 0, 0, 0);
        }
    }

    int r0 = rowbase + quad * 4;
    float di[4];
#pragma unroll
    for (int r = 0; r < 4; r++) {
        int rr = r0 + r;
        di[r] = dinv[rr < n ? rr : 0];
    }
    bool odd = lane & 1;
#pragma unroll
    for (int ct = 0; ct < 3; ct++) {
        float x0 = acc[ct][0], x1 = acc[ct][1], x2 = acc[ct][2], x3 = acc[ct][3];
        float y0 = __shfl_xor(x0, 1, 64), y1 = __shfl_xor(x1, 1, 64);
        float y2 = __shfl_xor(x2, 1, 64), y3 = __shfl_xor(x3, 1, 64);
        int colp = ct * 16 + (c & ~1);
        if (colp >= 40) continue;
        if (!odd) {
            if (r0 + 0 < n) *(uint32_t*)(&G[(size_t)(r0 + 0) * 40 + colp]) = pack2bf(di[0] * x0, di[0] * y0);
            if (r0 + 1 < n) *(uint32_t*)(&G[(size_t)(r0 + 1) * 40 + colp]) = pack2bf(di[1] * x1, di[1] * y1);
        } else {
            if (r0 + 2 < n) *(uint32_t*)(&G[(size_t)(r0 + 2) * 40 + colp]) = pack2bf(di[2] * y2, di[2] * x2);
            if (r0 + 3 < n) *(uint32_t*)(&G[(size_t)(r0 + 3) * 40 + colp]) = pack2bf(di[3] * y3, di[3] * x3);
        }
    }
}

// ---------- D6: layer-1 aggregate, UNSCALED H1 with per-edge dinv[s] ----------
__global__ __launch_bounds__(256) void agg128_l1(const unsigned short* __restrict__ G,
                                                 const int* __restrict__ row_ptr,
                                                 const int* __restrict__ deg,
                                                 const unsigned short* __restrict__ csr_src,
                                                 const float* __restrict__ dinv,
                                                 const float* __restrict__ b,
                                                 unsigned short* __restrict__ Y, int n) {
    int node = blockIdx.x * 4 + (threadIdx.x >> 6);
    if (node >= n) return;
    int l = threadIdx.x & 63;
    const uint32_t* Gr = (const uint32_t*)G;

    float dn = dinv[node];
    float2 sf = bfp2f2(Gr[(size_t)node * 64 + l]);
    float2 acc = make_float2(dn * sf.x, dn * sf.y);  // self: dinv[d]*H1[d]
    int p = row_ptr[node];
    int p1 = p + deg[node];
    for (; p + 7 < p1; p += 8) {
        int s0 = csr_src[p],     s1 = csr_src[p + 1], s2 = csr_src[p + 2], s3 = csr_src[p + 3];
        int s4 = csr_src[p + 4], s5 = csr_src[p + 5], s6 = csr_src[p + 6], s7 = csr_src[p + 7];
        float d0 = dinv[s0], d1 = dinv[s1], d2 = dinv[s2], d3 = dinv[s3];
        float d4 = dinv[s4], d5 = dinv[s5], d6 = dinv[s6], d7 = dinv[s7];
        float2 f0 = bfp2f2(Gr[(size_t)s0 * 64 + l]), f1 = bfp2f2(Gr[(size_t)s1 * 64 + l]);
        float2 f2 = bfp2f2(Gr[(size_t)s2 * 64 + l]), f3 = bfp2f2(Gr[(size_t)s3 * 64 + l]);
        float2 f4 = bfp2f2(Gr[(size_t)s4 * 64 + l]), f5 = bfp2f2(Gr[(size_t)s5 * 64 + l]);
        float2 f6 = bfp2f2(Gr[(size_t)s6 * 64 + l]), f7 = bfp2f2(Gr[(size_t)s7 * 64 + l]);
        acc.x += (fmaf(d0, f0.x, d1 * f1.x) + fmaf(d2, f2.x, d3 * f3.x)) +
                 (fmaf(d4, f4.x, d5 * f5.x) + fmaf(d6, f6.x, d7 * f7.x));
        acc.y += (fmaf(d0, f0.y, d1 * f1.y) + fmaf(d2, f2.y, d3 * f3.y)) +
                 (fmaf(d4, f4.y, d5 * f5.y) + fmaf(d6, f6.y, d7 * f7.y));
    }
    for (; p < p1; ++p) {
        int s = csr_src[p];
        float ds = dinv[s];
        float2 f = bfp2f2(Gr[(size_t)s * 64 + l]);
        acc.x = fmaf(ds, f.x, acc.x);
        acc.y = fmaf(ds, f.y, acc.y);
    }
    float vx = fmaf(dn, acc.x, b[2 * l]);
    float vy = fmaf(dn, acc.y, b[2 * l + 1]);
    ((uint32_t*)Y)[(size_t)node * 64 + l] = pack2bf(vx > 0.f ? vx : 0.f, vy > 0.f ? vy : 0.f);
}

// ---------- D8: layer-2 aggregate (G pre-scaled) ----------
__global__ __launch_bounds__(256) void agg128(const unsigned short* __restrict__ G,
                                              const int* __restrict__ row_ptr,
                                              const int* __restrict__ deg,
                                              const unsigned short* __restrict__ csr_src,
                                              const float* __restrict__ dinv,
                                              const float* __restrict__ b,
                                              unsigned short* __restrict__ Y, int n) {
    int node = blockIdx.x * 4 + (threadIdx.x >> 6);
    if (node >= n) return;
    int l = threadIdx.x & 63;
    const uint32_t* Gr = (const uint32_t*)G;

    float2 acc = bfp2f2(Gr[(size_t)node * 64 + l]);  // self (pre-scaled)
    int p = row_ptr[node];
    int p1 = p + deg[node];
    for (; p + 7 < p1; p += 8) {
        int s0 = csr_src[p],     s1 = csr_src[p + 1], s2 = csr_src[p + 2], s3 = csr_src[p + 3];
        int s4 = csr_src[p + 4], s5 = csr_src[p + 5], s6 = csr_src[p + 6], s7 = csr_src[p + 7];
        float2 f0 = bfp2f2(Gr[(size_t)s0 * 64 + l]), f1 = bfp2f2(Gr[(size_t)s1 * 64 + l]);
        float2 f2 = bfp2f2(Gr[(size_t)s2 * 64 + l]), f3 = bfp2f2(Gr[(size_t)s3 * 64 + l]);
        float2 f4 = bfp2f2(Gr[(size_t)s4 * 64 + l]), f5 = bfp2f2(Gr[(size_t)s5 * 64 + l]);
        float2 f6 = bfp2f2(Gr[(size_t)s6 * 64 + l]), f7 = bfp2f2(Gr[(size_t)s7 * 64 + l]);
        acc.x += ((f0.x + f1.x) + (f2.x + f3.x)) + ((f4.x + f5.x) + (f6.x + f7.x));
        acc.y += ((f0.y + f1.y) + (f2.y + f3.y)) + ((f4.y + f5.y) + (f6.y + f7.y));
    }
    for (; p < p1; ++p) {
        float2 f = bfp2f2(Gr[(size_t)csr_src[p] * 64 + l]);
        acc.x += f.x; acc.y += f.y;
    }
    float dn = dinv[node];
    float vx = fmaf(dn, acc.x, b[2 * l]);
    float vy = fmaf(dn, acc.y, b[2 * l + 1]);
    ((uint32_t*)Y)[(size_t)node * 64 + l] = pack2bf(vx > 0.f ? vx : 0.f, vy > 0.f ? vy : 0.f);
}

// ---------- D10: 40-wide aggregate + log_softmax ----------
__global__ __launch_bounds__(256) void agg40_lsm(const unsigned short* __restrict__ G,
                                                 const int* __restrict__ row_ptr,
                                                 const int* __restrict__ deg,
                                                 const unsigned short* __restrict__ csr_src,
                                                 const float* __restrict__ dinv,
                                                 const float* __restrict__ b,
                                                 float* __restrict__ Y, int n) {
    int node = blockIdx.x * 4 + (threadIdx.x >> 6);
    if (node >= n) return;
    int lane = threadIdx.x & 63;
    bool act = lane < 40;
    int lc = act ? lane : 0;

    float acc = act ? bf2f(G[(size_t)node * 40 + lane]) : 0.f;
    int p = row_ptr[node];
    int p1 = p + deg[node];
    for (; p + 3 < p1; p += 4) {
        int s0 = csr_src[p], s1 = csr_src[p + 1], s2 = csr_src[p + 2], s3 = csr_src[p + 3];
        float f0 = bf2f(G[(size_t)s0 * 40 + lc]);
        float f1 = bf2f(G[(size_t)s1 * 40 + lc]);
        float f2 = bf2f(G[(size_t)s2 * 40 + lc]);
        float f3 = bf2f(G[(size_t)s3 * 40 + lc]);
        acc += (f0 + f1) + (f2 + f3);
    }
    for (; p < p1; ++p) acc += bf2f(G[(size_t)csr_src[p] * 40 + lc]);

    float v = act ? fmaf(dinv[node], acc, b[lane]) : -1e30f;
    float m = v;
#pragma unroll
    for (int off = 32; off > 0; off >>= 1) m = fmaxf(m, __shfl_xor(m, off, 64));
    float ex = act ? expf(v - m) : 0.f;
    float s_ = ex;
#pragma unroll
    for (int off = 32; off > 0; off >>= 1) s_ += __shfl_xor(s_, off, 64);
    float ls = logf(s_);
    if (act) Y[(size_t)node * 40 + lane] = v - m - ls;
}

// ---------- launch ----------

extern "C" void kernel_launch(void* const* d_in, const int* in_sizes, int n_in,
                              void* d_out, int out_size, void* d_ws, size_t ws_size,
                              hipStream_t stream) {
    const float* x  = (const float*)d_in[0];
    const int*   ei = (const int*)d_in[1];
    const float* W1 = (const float*)d_in[2];
    const float* b1 = (const float*)d_in[3];
    const float* W2 = (const float*)d_in[4];
    const float* b2 = (const float*)d_in[5];
    const float* W3 = (const float*)d_in[6];
    const float* b3 = (const float*)d_in[7];
    float* out = (float*)d_out;

    const int n = NN, e = NE;
    const int* srcI = ei;
    const int* dstI = ei + e;

    char* ws = (char*)d_ws;
    int*            deg     = (int*)ws;                          // n ints
    int*            row_ptr = (int*)(ws + 200704);               // n ints
    float*          dinv    = (float*)(ws + 401408);             // n fp32
    int*            base196 = (int*)(ws + 602112);               // NB+1 ints
    int*            counts  = (int*)(ws + 603136);               // NB*TB ints (~77KB)
    uint32_t*       packA   = (uint32_t*)(ws + 681984);          // E uint32 (3.2MB)
    unsigned short* csr_src = (unsigned short*)(ws + 3881984);   // E ushort (1.6MB)
    unsigned short* WT1     = (unsigned short*)(ws + 5481984);   // 128x128 bf16
    unsigned short* WT2     = (unsigned short*)(ws + 5514752);
    unsigned short* WT3     = (unsigned short*)(ws + 5547520);   // 48x128 bf16
    unsigned short* bufG    = (unsigned short*)(ws + 5559808);   // n*128 bf16
    unsigned short* bufA    = (unsigned short*)(ws + 18359808);  // n*128 bf16

    // D1: W transposes
    prep<<<152, 256, 0, stream>>>(W1, W2, W3, WT1, WT2, WT3);
    // D2: layer-1 GEMM (unscaled) ∪ coarse LDS histogram
    gemm1_hist<<<GG + TB, 256, 0, stream>>>(x, WT1, bufG, n, dstI, counts, e);
    // D3: scan counts + bucket bases
    scanA<<<1, 256, 0, stream>>>(counts, base196);
    // D4: partition edges into hi buckets
    scatterA<<<TB, 256, 0, stream>>>(srcI, dstI, counts, base196, packA, e);
    // D5: per-bucket sort -> CSR + row_ptr/deg/dinv
    buildB<<<NB, 256, 0, stream>>>(packA, base196, row_ptr, deg, dinv, csr_src, n);
    // D6: aggregate layer 1 (per-edge dinv)
    agg128_l1<<<(n + 3) / 4, 256, 0, stream>>>(bufG, row_ptr, deg, csr_src, dinv, b1, bufA, n);
    // D7: layer-2 GEMM (pre-scaled)
    gemm128_mfma<<<GG, 256, 0, stream>>>(bufA, WT2, dinv, bufG, n);
    // D8: aggregate layer 2
    agg128<<<(n + 3) / 4, 256, 0, stream>>>(bufG, row_ptr, deg, csr_src, dinv, b2, bufA, n);
    // D9: layer-3 GEMM (40-wide, pre-scaled)
    gemm40_mfma<<<GG, 256, 0, stream>>>(bufA, WT3, dinv, bufG, n);
    // D10: aggregate + log_softmax -> out
    agg40_lsm<<<(n + 3) / 4, 256, 0, stream>>>(bufG, row_ptr, deg, csr_src, dinv, b3, out, n);
}

// Round 3
// 273.842 us; speedup vs baseline: 1.0842x; 1.0617x over previous
//
#include <hip/hip_runtime.h>
#include <stdint.h>

#define NN 50000
#define NE 800000
#define GG 782     // gemm grid: (NN + 63) / 64
#define NB 196     // hi buckets: ceil(NN / 256)
#define TT 2048    // edges per scatter block
#define SB 391     // scatter blocks: ceil(NE / TT)
#define SLAB 8192  // packA slab stride per bucket (mean 4096, sigma 64 -> 64-sigma headroom)

typedef __attribute__((ext_vector_type(8))) short bfx8;   // 8 bf16 (4 VGPRs)
typedef __attribute__((ext_vector_type(4))) float f32x4;  // MFMA acc

// ---- bf16 helpers (RNE) ----
__device__ inline unsigned short f2bf(float f) {
    union { float f; uint32_t u; } x; x.f = f;
    uint32_t u = x.u;
    return (unsigned short)((u + 0x7fffu + ((u >> 16) & 1u)) >> 16);
}
__device__ inline uint32_t pack2bf(float lo, float hi) {
    return (uint32_t)f2bf(lo) | ((uint32_t)f2bf(hi) << 16);
}
__device__ inline float bf2f(unsigned short h) {
    union { uint32_t u; float f; } c; c.u = ((uint32_t)h) << 16;
    return c.f;
}
__device__ inline float2 bfp2f2(uint32_t v) {
    union { uint32_t u; float f; } a, b;
    a.u = (v & 0xffffu) << 16;
    b.u = v & 0xffff0000u;
    return make_float2(a.f, b.f);
}
__device__ inline bfx8 ld8(const unsigned short* p) {
    union { uint4 u; bfx8 v; } c;
    c.u = *(const uint4*)p;
    return c.v;
}
__device__ inline bfx8 cvt8(float4 u, float4 v) {
    union { unsigned short s[8]; bfx8 r; } c;
    c.s[0] = f2bf(u.x); c.s[1] = f2bf(u.y); c.s[2] = f2bf(u.z); c.s[3] = f2bf(u.w);
    c.s[4] = f2bf(v.x); c.s[5] = f2bf(v.y); c.s[6] = f2bf(v.z); c.s[7] = f2bf(v.w);
    return c.r;
}

// ---------- D1: W transposes + zero bucket cursors ----------
__global__ void prep(const float* __restrict__ W1, const float* __restrict__ W2,
                     const float* __restrict__ W3,
                     unsigned short* __restrict__ WT1, unsigned short* __restrict__ WT2,
                     unsigned short* __restrict__ WT3, int* __restrict__ cursor) {
    if (blockIdx.x == 152) {
        if (threadIdx.x < NB) cursor[threadIdx.x] = 0;
        return;
    }
    int w = blockIdx.x * 256 + threadIdx.x;
    if (w < 16384) {
        int nn = w >> 7, k = w & 127;
        WT1[nn * 128 + k] = f2bf(W1[k * 128 + nn]);
    } else if (w < 32768) {
        int w2 = w - 16384, nn = w2 >> 7, k = w2 & 127;
        WT2[nn * 128 + k] = f2bf(W2[k * 128 + nn]);
    } else if (w < 38912) {
        int w2 = w - 32768, nn = w2 >> 7, k = w2 & 127;  // 48x128, zero-pad
        WT3[nn * 128 + k] = (nn < 40) ? f2bf(W3[k * 40 + nn]) : (unsigned short)0;
    }
}

// ---------- D2: layer-1 GEMM ∪ bucket-scatter (cursor-reservation, no pre-scan) ----------
// R2 post-mortem: count/scan/scatter chain had awful parallelism (1-block scan,
// 98-block scatter) and 2 extra launch gaps. Replaced by direct scatter into
// per-bucket slabs: each block LDS-ranks its 2048 edges, reserves slab space
// with ONE global atomicAdd per (block,bucket) (77K total ~ 4us of atomic
// traffic at R1's measured rate, vs 800K), writes packed edges. Fully
// overlaps the ~14us GEMM in the same dispatch.
__global__ __launch_bounds__(256) void gemm1_hist(const float* __restrict__ X,
                                                  const unsigned short* __restrict__ WT,
                                                  unsigned short* __restrict__ G, int n,
                                                  const int* __restrict__ src,
                                                  const int* __restrict__ dst,
                                                  int* __restrict__ cursor,
                                                  uint32_t* __restrict__ packA, int e) {
    __shared__ int lc[NB];
    __shared__ int gb[NB];
    if (blockIdx.x >= GG) {
        int b = blockIdx.x - GG;
        int t = threadIdx.x;
        if (t < NB) lc[t] = 0;
        __syncthreads();
        int start = b * TT;
        int end = start + TT; if (end > e) end = e;
        int hi_[8], r_[8];
        uint32_t pk_[8];
#pragma unroll
        for (int j = 0; j < 8; j++) {
            int i = start + j * 256 + t;
            if (i < end) {
                int dd = dst[i], ss = src[i];
                hi_[j] = dd >> 8;
                pk_[j] = ((uint32_t)dd << 16) | (uint32_t)ss;
                r_[j] = atomicAdd(&lc[hi_[j]], 1);  // LDS rank
            } else r_[j] = -1;
        }
        __syncthreads();
        if (t < NB) {
            int c = lc[t];
            gb[t] = c ? atomicAdd(&cursor[t], c) : 0;  // global slab reservation
        }
        __syncthreads();
#pragma unroll
        for (int j = 0; j < 8; j++) {
            if (r_[j] >= 0)
                packA[(size_t)hi_[j] * SLAB + gb[hi_[j]] + r_[j]] = pk_[j];
        }
        return;
    }
    int wave = threadIdx.x >> 6;
    int lane = threadIdx.x & 63;
    int quad = lane >> 4;
    int c = lane & 15;
    int rowbase = blockIdx.x * 64 + wave * 16;

    int arow = rowbase + c;
    if (arow >= n) arow = n - 1;
    const float* ap = X + (size_t)arow * 128 + quad * 8;
    bfx8 a[4];
#pragma unroll
    for (int kc = 0; kc < 4; kc++) {
        float4 u = *(const float4*)(ap + kc * 32);
        float4 v = *(const float4*)(ap + kc * 32 + 4);
        a[kc] = cvt8(u, v);
    }

    f32x4 acc[8];
#pragma unroll
    for (int ct = 0; ct < 8; ct++) acc[ct] = (f32x4){0.f, 0.f, 0.f, 0.f};
#pragma unroll
    for (int ct = 0; ct < 8; ct++) {
        const unsigned short* bp = WT + (size_t)(ct * 16 + c) * 128 + quad * 8;
#pragma unroll
        for (int kc = 0; kc < 4; kc++) {
            bfx8 b = ld8(bp + kc * 32);
            acc[ct] = __builtin_amdgcn_mfma_f32_16x16x32_bf16(a[kc], b, acc[ct], 0, 0, 0);
        }
    }

    int r0 = rowbase + quad * 4;
    bool odd = lane & 1;
#pragma unroll
    for (int ct = 0; ct < 8; ct++) {
        float x0 = acc[ct][0], x1 = acc[ct][1], x2 = acc[ct][2], x3 = acc[ct][3];
        float y0 = __shfl_xor(x0, 1, 64), y1 = __shfl_xor(x1, 1, 64);
        float y2 = __shfl_xor(x2, 1, 64), y3 = __shfl_xor(x3, 1, 64);
        int colp = ct * 16 + (c & ~1);
        if (!odd) {
            if (r0 + 0 < n) *(uint32_t*)(&G[(size_t)(r0 + 0) * 128 + colp]) = pack2bf(x0, y0);
            if (r0 + 1 < n) *(uint32_t*)(&G[(size_t)(r0 + 1) * 128 + colp]) = pack2bf(x1, y1);
        } else {
            if (r0 + 2 < n) *(uint32_t*)(&G[(size_t)(r0 + 2) * 128 + colp]) = pack2bf(y2, x2);
            if (r0 + 3 < n) *(uint32_t*)(&G[(size_t)(r0 + 3) * 128 + colp]) = pack2bf(y3, x3);
        }
    }
}

// ---------- D3: per-bucket fine sort -> row_ptr/deg/dinv + csr_src ----------
// Each block redundantly scans the 196 bucket counts (tiny) for its base,
// then two LDS-atomic passes over its slab.
__global__ __launch_bounds__(256) void buildB(const uint32_t* __restrict__ packA,
                                              const int* __restrict__ cursor,
                                              int* __restrict__ row_ptr, int* __restrict__ deg,
                                              float* __restrict__ dinv,
                                              unsigned short* __restrict__ csr_src, int n) {
    __shared__ int s[256];
    __shared__ int cnt[256];
    __shared__ int rp[256];
    __shared__ int basehi, bcnt;
    int hi = blockIdx.x;
    int t = threadIdx.x;
    int bc = (t < NB) ? cursor[t] : 0;
    s[t] = bc;
    __syncthreads();
#pragma unroll
    for (int off = 1; off < 256; off <<= 1) {
        int y = (t >= off) ? s[t - off] : 0;
        __syncthreads();
        s[t] += y;
        __syncthreads();
    }
    if (t == hi) { basehi = s[t] - bc; bcnt = bc; }
    cnt[t] = 0;
    __syncthreads();
    int b0 = basehi;
    int mc = bcnt;
    const uint32_t* slab = packA + (size_t)hi * SLAB;
    for (int i = t; i < mc; i += 256)
        atomicAdd(&cnt[(slab[i] >> 16) & 0xFF], 1);  // LDS
    __syncthreads();
    int v = cnt[t];
    s[t] = v;
    __syncthreads();
#pragma unroll
    for (int off = 1; off < 256; off <<= 1) {
        int y = (t >= off) ? s[t - off] : 0;
        __syncthreads();
        s[t] += y;
        __syncthreads();
    }
    rp[t] = b0 + s[t] - v;  // absolute row start for node hi*256+t
    int node = hi * 256 + t;
    if (node < n) {
        row_ptr[node] = rp[t];
        deg[node] = v;
        dinv[node] = rsqrtf(1.0f + (float)v);
    }
    cnt[t] = 0;
    __syncthreads();
    for (int i = t; i < mc; i += 256) {
        uint32_t p = slab[i];
        int lo = (p >> 16) & 0xFF;
        int r = atomicAdd(&cnt[lo], 1);  // LDS
        csr_src[rp[lo] + r] = (unsigned short)(p & 0xFFFF);
    }
}

// ---------- GEMMs for layers 2/3: pre-scale rows by dinv (epilogue) ----------
__global__ __launch_bounds__(256) void gemm128_mfma(const unsigned short* __restrict__ A,
                                                    const unsigned short* __restrict__ WT,
                                                    const float* __restrict__ dinv,
                                                    unsigned short* __restrict__ G, int n) {
    int wave = threadIdx.x >> 6;
    int lane = threadIdx.x & 63;
    int quad = lane >> 4;
    int c = lane & 15;
    int rowbase = blockIdx.x * 64 + wave * 16;

    int arow = rowbase + c;
    if (arow >= n) arow = n - 1;
    const unsigned short* ap = A + (size_t)arow * 128 + quad * 8;
    bfx8 a[4];
#pragma unroll
    for (int kc = 0; kc < 4; kc++) a[kc] = ld8(ap + kc * 32);

    f32x4 acc[8];
#pragma unroll
    for (int ct = 0; ct < 8; ct++) acc[ct] = (f32x4){0.f, 0.f, 0.f, 0.f};
#pragma unroll
    for (int ct = 0; ct < 8; ct++) {
        const unsigned short* bp = WT + (size_t)(ct * 16 + c) * 128 + quad * 8;
#pragma unroll
        for (int kc = 0; kc < 4; kc++) {
            bfx8 b = ld8(bp + kc * 32);
            acc[ct] = __builtin_amdgcn_mfma_f32_16x16x32_bf16(a[kc], b, acc[ct], 0, 0, 0);
        }
    }

    int r0 = rowbase + quad * 4;
    float di[4];
#pragma unroll
    for (int r = 0; r < 4; r++) {
        int rr = r0 + r;
        di[r] = dinv[rr < n ? rr : 0];
    }
    bool odd = lane & 1;
#pragma unroll
    for (int ct = 0; ct < 8; ct++) {
        float x0 = acc[ct][0], x1 = acc[ct][1], x2 = acc[ct][2], x3 = acc[ct][3];
        float y0 = __shfl_xor(x0, 1, 64), y1 = __shfl_xor(x1, 1, 64);
        float y2 = __shfl_xor(x2, 1, 64), y3 = __shfl_xor(x3, 1, 64);
        int colp = ct * 16 + (c & ~1);
        if (!odd) {
            if (r0 + 0 < n) *(uint32_t*)(&G[(size_t)(r0 + 0) * 128 + colp]) = pack2bf(di[0] * x0, di[0] * y0);
            if (r0 + 1 < n) *(uint32_t*)(&G[(size_t)(r0 + 1) * 128 + colp]) = pack2bf(di[1] * x1, di[1] * y1);
        } else {
            if (r0 + 2 < n) *(uint32_t*)(&G[(size_t)(r0 + 2) * 128 + colp]) = pack2bf(di[2] * y2, di[2] * x2);
            if (r0 + 3 < n) *(uint32_t*)(&G[(size_t)(r0 + 3) * 128 + colp]) = pack2bf(di[3] * y3, di[3] * x3);
        }
    }
}

__global__ __launch_bounds__(256) void gemm40_mfma(const unsigned short* __restrict__ A,
                                                   const unsigned short* __restrict__ WT,
                                                   const float* __restrict__ dinv,
                                                   unsigned short* __restrict__ G, int n) {
    int wave = threadIdx.x >> 6;
    int lane = threadIdx.x & 63;
    int quad = lane >> 4;
    int c = lane & 15;
    int rowbase = blockIdx.x * 64 + wave * 16;

    int arow = rowbase + c;
    if (arow >= n) arow = n - 1;
    const unsigned short* ap = A + (size_t)arow * 128 + quad * 8;
    bfx8 a[4];
#pragma unroll
    for (int kc = 0; kc < 4; kc++) a[kc] = ld8(ap + kc * 32);

    f32x4 acc[3];
#pragma unroll
    for (int ct = 0; ct < 3; ct++) acc[ct] = (f32x4){0.f, 0.f, 0.f, 0.f};
#pragma unroll
    for (int ct = 0; ct < 3; ct++) {
        const unsigned short* bp = WT + (size_t)(ct * 16 + c) * 128 + quad * 8;
#pragma unroll
        for (int kc = 0; kc < 4; kc++) {
            bfx8 b = ld8(bp + kc * 32);
            acc[ct] = __builtin_amdgcn_mfma_f32_16x16x32_bf16(a[kc], b, acc[ct], 0, 0, 0);
        }
    }

    int r0 = rowbase + quad * 4;
    float di[4];
#pragma unroll
    for (int r = 0; r < 4; r++) {
        int rr = r0 + r;
        di[r] = dinv[rr < n ? rr : 0];
    }
    bool odd = lane & 1;
#pragma unroll
    for (int ct = 0; ct < 3; ct++) {
        float x0 = acc[ct][0], x1 = acc[ct][1], x2 = acc[ct][2], x3 = acc[ct][3];
        float y0 = __shfl_xor(x0, 1, 64), y1 = __shfl_xor(x1, 1, 64);
        float y2 = __shfl_xor(x2, 1, 64), y3 = __shfl_xor(x3, 1, 64);
        int colp = ct * 16 + (c & ~1);
        if (colp >= 40) continue;
        if (!odd) {
            if (r0 + 0 < n) *(uint32_t*)(&G[(size_t)(r0 + 0) * 40 + colp]) = pack2bf(di[0] * x0, di[0] * y0);
            if (r0 + 1 < n) *(uint32_t*)(&G[(size_t)(r0 + 1) * 40 + colp]) = pack2bf(di[1] * x1, di[1] * y1);
        } else {
            if (r0 + 2 < n) *(uint32_t*)(&G[(size_t)(r0 + 2) * 40 + colp]) = pack2bf(di[2] * y2, di[2] * x2);
            if (r0 + 3 < n) *(uint32_t*)(&G[(size_t)(r0 + 3) * 40 + colp]) = pack2bf(di[3] * y3, di[3] * x3);
        }
    }
}

// ---------- D4: layer-1 aggregate, UNSCALED H1 with per-edge dinv[s] ----------
__global__ __launch_bounds__(256) void agg128_l1(const unsigned short* __restrict__ G,
                                                 const int* __restrict__ row_ptr,
                                                 const int* __restrict__ deg,
                                                 const unsigned short* __restrict__ csr_src,
                                                 const float* __restrict__ dinv,
                                                 const float* __restrict__ b,
                                                 unsigned short* __restrict__ Y, int n) {
    int node = blockIdx.x * 4 + (threadIdx.x >> 6);
    if (node >= n) return;
    int l = threadIdx.x & 63;
    const uint32_t* Gr = (const uint32_t*)G;

    float dn = dinv[node];
    float2 sf = bfp2f2(Gr[(size_t)node * 64 + l]);
    float2 acc = make_float2(dn * sf.x, dn * sf.y);  // self: dinv[d]*H1[d]
    int p = row_ptr[node];
    int p1 = p + deg[node];
    for (; p + 7 < p1; p += 8) {
        int s0 = csr_src[p],     s1 = csr_src[p + 1], s2 = csr_src[p + 2], s3 = csr_src[p + 3];
        int s4 = csr_src[p + 4], s5 = csr_src[p + 5], s6 = csr_src[p + 6], s7 = csr_src[p + 7];
        float d0 = dinv[s0], d1 = dinv[s1], d2 = dinv[s2], d3 = dinv[s3];
        float d4 = dinv[s4], d5 = dinv[s5], d6 = dinv[s6], d7 = dinv[s7];
        float2 f0 = bfp2f2(Gr[(size_t)s0 * 64 + l]), f1 = bfp2f2(Gr[(size_t)s1 * 64 + l]);
        float2 f2 = bfp2f2(Gr[(size_t)s2 * 64 + l]), f3 = bfp2f2(Gr[(size_t)s3 * 64 + l]);
        float2 f4 = bfp2f2(Gr[(size_t)s4 * 64 + l]), f5 = bfp2f2(Gr[(size_t)s5 * 64 + l]);
        float2 f6 = bfp2f2(Gr[(size_t)s6 * 64 + l]), f7 = bfp2f2(Gr[(size_t)s7 * 64 + l]);
        acc.x += (fmaf(d0, f0.x, d1 * f1.x) + fmaf(d2, f2.x, d3 * f3.x)) +
                 (fmaf(d4, f4.x, d5 * f5.x) + fmaf(d6, f6.x, d7 * f7.x));
        acc.y += (fmaf(d0, f0.y, d1 * f1.y) + fmaf(d2, f2.y, d3 * f3.y)) +
                 (fmaf(d4, f4.y, d5 * f5.y) + fmaf(d6, f6.y, d7 * f7.y));
    }
    for (; p < p1; ++p) {
        int s = csr_src[p];
        float ds = dinv[s];
        float2 f = bfp2f2(Gr[(size_t)s * 64 + l]);
        acc.x = fmaf(ds, f.x, acc.x);
        acc.y = fmaf(ds, f.y, acc.y);
    }
    float vx = fmaf(dn, acc.x, b[2 * l]);
    float vy = fmaf(dn, acc.y, b[2 * l + 1]);
    ((uint32_t*)Y)[(size_t)node * 64 + l] = pack2bf(vx > 0.f ? vx : 0.f, vy > 0.f ? vy : 0.f);
}

// ---------- D6: layer-2 aggregate (G pre-scaled) ----------
__global__ __launch_bounds__(256) void agg128(const unsigned short* __restrict__ G,
                                              const int* __restrict__ row_ptr,
                                              const int* __restrict__ deg,
                                              const unsigned short* __restrict__ csr_src,
                                              const float* __restrict__ dinv,
                                              const float* __restrict__ b,
                                              unsigned short* __restrict__ Y, int n) {
    int node = blockIdx.x * 4 + (threadIdx.x >> 6);
    if (node >= n) return;
    int l = threadIdx.x & 63;
    const uint32_t* Gr = (const uint32_t*)G;

    float2 acc = bfp2f2(Gr[(size_t)node * 64 + l]);  // self (pre-scaled)
    int p = row_ptr[node];
    int p1 = p + deg[node];
    for (; p + 7 < p1; p += 8) {
        int s0 = csr_src[p],     s1 = csr_src[p + 1], s2 = csr_src[p + 2], s3 = csr_src[p + 3];
        int s4 = csr_src[p + 4], s5 = csr_src[p + 5], s6 = csr_src[p + 6], s7 = csr_src[p + 7];
        float2 f0 = bfp2f2(Gr[(size_t)s0 * 64 + l]), f1 = bfp2f2(Gr[(size_t)s1 * 64 + l]);
        float2 f2 = bfp2f2(Gr[(size_t)s2 * 64 + l]), f3 = bfp2f2(Gr[(size_t)s3 * 64 + l]);
        float2 f4 = bfp2f2(Gr[(size_t)s4 * 64 + l]), f5 = bfp2f2(Gr[(size_t)s5 * 64 + l]);
        float2 f6 = bfp2f2(Gr[(size_t)s6 * 64 + l]), f7 = bfp2f2(Gr[(size_t)s7 * 64 + l]);
        acc.x += ((f0.x + f1.x) + (f2.x + f3.x)) + ((f4.x + f5.x) + (f6.x + f7.x));
        acc.y += ((f0.y + f1.y) + (f2.y + f3.y)) + ((f4.y + f5.y) + (f6.y + f7.y));
    }
    for (; p < p1; ++p) {
        float2 f = bfp2f2(Gr[(size_t)csr_src[p] * 64 + l]);
        acc.x += f.x; acc.y += f.y;
    }
    float dn = dinv[node];
    float vx = fmaf(dn, acc.x, b[2 * l]);
    float vy = fmaf(dn, acc.y, b[2 * l + 1]);
    ((uint32_t*)Y)[(size_t)node * 64 + l] = pack2bf(vx > 0.f ? vx : 0.f, vy > 0.f ? vy : 0.f);
}

// ---------- D8: 40-wide aggregate + log_softmax ----------
__global__ __launch_bounds__(256) void agg40_lsm(const unsigned short* __restrict__ G,
                                                 const int* __restrict__ row_ptr,
                                                 const int* __restrict__ deg,
                                                 const unsigned short* __restrict__ csr_src,
                                                 const float* __restrict__ dinv,
                                                 const float* __restrict__ b,
                                                 float* __restrict__ Y, int n) {
    int node = blockIdx.x * 4 + (threadIdx.x >> 6);
    if (node >= n) return;
    int lane = threadIdx.x & 63;
    bool act = lane < 40;
    int lc = act ? lane : 0;

    float acc = act ? bf2f(G[(size_t)node * 40 + lane]) : 0.f;
    int p = row_ptr[node];
    int p1 = p + deg[node];
    for (; p + 3 < p1; p += 4) {
        int s0 = csr_src[p], s1 = csr_src[p + 1], s2 = csr_src[p + 2], s3 = csr_src[p + 3];
        float f0 = bf2f(G[(size_t)s0 * 40 + lc]);
        float f1 = bf2f(G[(size_t)s1 * 40 + lc]);
        float f2 = bf2f(G[(size_t)s2 * 40 + lc]);
        float f3 = bf2f(G[(size_t)s3 * 40 + lc]);
        acc += (f0 + f1) + (f2 + f3);
    }
    for (; p < p1; ++p) acc += bf2f(G[(size_t)csr_src[p] * 40 + lc]);

    float v = act ? fmaf(dinv[node], acc, b[lane]) : -1e30f;
    float m = v;
#pragma unroll
    for (int off = 32; off > 0; off >>= 1) m = fmaxf(m, __shfl_xor(m, off, 64));
    float ex = act ? expf(v - m) : 0.f;
    float s_ = ex;
#pragma unroll
    for (int off = 32; off > 0; off >>= 1) s_ += __shfl_xor(s_, off, 64);
    float ls = logf(s_);
    if (act) Y[(size_t)node * 40 + lane] = v - m - ls;
}

// ---------- launch ----------

extern "C" void kernel_launch(void* const* d_in, const int* in_sizes, int n_in,
                              void* d_out, int out_size, void* d_ws, size_t ws_size,
                              hipStream_t stream) {
    const float* x  = (const float*)d_in[0];
    const int*   ei = (const int*)d_in[1];
    const float* W1 = (const float*)d_in[2];
    const float* b1 = (const float*)d_in[3];
    const float* W2 = (const float*)d_in[4];
    const float* b2 = (const float*)d_in[5];
    const float* W3 = (const float*)d_in[6];
    const float* b3 = (const float*)d_in[7];
    float* out = (float*)d_out;

    const int n = NN, e = NE;
    const int* srcI = ei;
    const int* dstI = ei + e;

    char* ws = (char*)d_ws;
    int*            deg     = (int*)ws;                          // n ints
    int*            row_ptr = (int*)(ws + 200704);               // n ints
    float*          dinv    = (float*)(ws + 401408);             // n fp32
    int*            cursor  = (int*)(ws + 602112);               // NB ints
    uint32_t*       packA   = (uint32_t*)(ws + 603136);          // NB*SLAB uint32 (6.4MB)
    unsigned short* csr_src = (unsigned short*)(ws + 7025664);   // E ushort (1.6MB)
    unsigned short* WT1     = (unsigned short*)(ws + 8625664);   // 128x128 bf16
    unsigned short* WT2     = (unsigned short*)(ws + 8658432);
    unsigned short* WT3     = (unsigned short*)(ws + 8691200);   // 48x128 bf16
    unsigned short* bufG    = (unsigned short*)(ws + 8703488);   // n*128 bf16
    unsigned short* bufA    = (unsigned short*)(ws + 21503488);  // n*128 bf16

    // D1: W transposes + zero cursors
    prep<<<153, 256, 0, stream>>>(W1, W2, W3, WT1, WT2, WT3, cursor);
    // D2: layer-1 GEMM (unscaled) ∪ slab scatter
    gemm1_hist<<<GG + SB, 256, 0, stream>>>(x, WT1, bufG, n, srcI, dstI, cursor, packA, e);
    // D3: per-bucket sort -> CSR + row_ptr/deg/dinv
    buildB<<<NB, 256, 0, stream>>>(packA, cursor, row_ptr, deg, dinv, csr_src, n);
    // D4: aggregate layer 1 (per-edge dinv)
    agg128_l1<<<(n + 3) / 4, 256, 0, stream>>>(bufG, row_ptr, deg, csr_src, dinv, b1, bufA, n);
    // D5: layer-2 GEMM (pre-scaled)
    gemm128_mfma<<<GG, 256, 0, stream>>>(bufA, WT2, dinv, bufG, n);
    // D6: aggregate layer 2
    agg128<<<(n + 3) / 4, 256, 0, stream>>>(bufG, row_ptr, deg, csr_src, dinv, b2, bufA, n);
    // D7: layer-3 GEMM (40-wide, pre-scaled)
    gemm40_mfma<<<GG, 256, 0, stream>>>(bufA, WT3, dinv, bufG, n);
    // D8: aggregate + log_softmax -> out
    agg40_lsm<<<(n + 3) / 4, 256, 0, stream>>>(bufG, row_ptr, deg, csr_src, dinv, b3, out, n);
}